// Round 8
// baseline (763.088 us; speedup 1.0000x reference)
//
#include <hip/hip_runtime.h>
#include <hip/hip_bf16.h>
#include <cstddef>

#define MM     281
#define NSEQ   33049
#define BB     4
#define NH     32768          // NSEQ - MM
#define NTOT   (BB*NSEQ)      // 132196
#define MPAD   288
#define NSP    32             // key splits for p-attention
#define SCALEQ 0.125f
#define LORAS  2.0f

typedef __attribute__((ext_vector_type(8))) short bf16x8;
typedef __attribute__((ext_vector_type(4))) float f32x4;

static __device__ __forceinline__ short f2bf(float v){
  __hip_bfloat16 h = __float2bfloat16(v);
  return *reinterpret_cast<short*>(&h);
}
static __device__ __forceinline__ float bf2f(short v){
  return __uint_as_float((unsigned)(unsigned short)v << 16);
}

// ---------------- K0: fold LoRA + scales into combined bf16 weight matrix ----------------
__global__ void k_weights(const float* __restrict__ qW, const float* __restrict__ qb,
                          const float* __restrict__ qA, const float* __restrict__ qB,
                          const float* __restrict__ kvW, const float* __restrict__ kvb,
                          const float* __restrict__ kvA, const float* __restrict__ kvB,
                          const float* __restrict__ resW, const float* __restrict__ resw,
                          short* __restrict__ WcB, float* __restrict__ bc){
  int j = blockIdx.x;     // 0..511
  int c = threadIdx.x;    // 0..255
  float w;
  if (j < 128){
    float l = 0.f;
    #pragma unroll
    for (int r = 0; r < 8; ++r) l += qA[j*8+r]*qB[r*256+c];
    w = SCALEQ*(qW[j*256+c] + LORAS*l);
    if (c==0) bc[j] = SCALEQ*qb[j];
  } else if (j < 384){
    int jj = j-128;
    float l = 0.f;
    #pragma unroll
    for (int r = 0; r < 8; ++r) l += kvA[jj*8+r]*kvB[r*256+c];
    w = kvW[jj*256+c] + LORAS*l;
    if (c==0) bc[j] = kvb[jj];
  } else {
    int jj = j-384;
    w = resw[0]*resW[jj*256+c];
    if (c==0) bc[j] = 0.f;
  }
  WcB[j*256+c] = f2bf(w);
}

// ---------------- K0b: X f32 -> bf16 (streaming) ----------------
__global__ __launch_bounds__(256) void k_cvtx(const float* __restrict__ X,
                                              short* __restrict__ XB){
  size_t i = ((size_t)blockIdx.x*256 + threadIdx.x)*8;
  if (i >= (size_t)NTOT*256) return;
  float4 u = *(const float4*)(X+i);
  float4 v = *(const float4*)(X+i+4);
  bf16x8 o = bf16x8{f2bf(u.x),f2bf(u.y),f2bf(u.z),f2bf(u.w),
                    f2bf(v.x),f2bf(v.y),f2bf(v.z),f2bf(v.w)};
  *(bf16x8*)(XB+i) = o;
}

// ---------------- K1: MFMA projection GEMM  Y = xb @ Wc.T + bc ----------------
__global__ __launch_bounds__(256) void k_proj3(const short* __restrict__ XB,
                       const short* __restrict__ WcB, const float* __restrict__ bc,
                       short* __restrict__ QB, short* __restrict__ KB,
                       short* __restrict__ VB, short* __restrict__ VhT,
                       short* __restrict__ RESHT, float* __restrict__ OUT){
  int tid = threadIdx.x;
  int wid = tid >> 6, lane = tid & 63;
  int lo = lane & 15, hi = lane >> 4;
  int m0 = blockIdx.x*32;

  f32x4 acc[2][8];
  #pragma unroll
  for (int mt=0;mt<2;++mt)
    #pragma unroll
    for (int nt=0;nt<8;++nt) acc[mt][nt] = f32x4{0.f,0.f,0.f,0.f};

  int r0 = m0 + lo;      if (r0 >= NTOT) r0 = NTOT-1;
  int r1 = m0 + 16 + lo; if (r1 >= NTOT) r1 = NTOT-1;
  const short* x0p = XB + (size_t)r0*256 + hi*8;
  const short* x1p = XB + (size_t)r1*256 + hi*8;

  #pragma unroll
  for (int ks=0; ks<8; ++ks){
    bf16x8 a0 = *(const bf16x8*)(x0p + ks*32);
    bf16x8 a1 = *(const bf16x8*)(x1p + ks*32);
    bf16x8 bfr[8];
    #pragma unroll
    for (int nt=0;nt<8;++nt){
      int jc = wid*128 + nt*16 + lo;
      bfr[nt] = *(const bf16x8*)(WcB + (size_t)jc*256 + ks*32 + hi*8);
    }
    #pragma unroll
    for (int nt=0;nt<8;++nt){
      acc[0][nt] = __builtin_amdgcn_mfma_f32_16x16x32_bf16(a0, bfr[nt], acc[0][nt], 0,0,0);
      acc[1][nt] = __builtin_amdgcn_mfma_f32_16x16x32_bf16(a1, bfr[nt], acc[1][nt], 0,0,0);
    }
  }

  float bias[8];
  #pragma unroll
  for (int nt=0;nt<8;++nt) bias[nt] = bc[wid*128 + nt*16 + lo];

  if (wid == 2 || wid == 3){
    #pragma unroll
    for (int mt=0;mt<2;++mt){
      int rbase = m0 + mt*16 + hi*4;
      int b = rbase / NSEQ;
      int m = rbase - b*NSEQ;
      bool fast = (rbase + 3 < NTOT) && (m >= MM) && (m + 4 <= NSEQ);
      #pragma unroll
      for (int nt=0;nt<8;++nt){
        int col = nt*16 + lo;
        float v0 = acc[mt][nt][0]+bias[nt], v1 = acc[mt][nt][1]+bias[nt];
        float v2 = acc[mt][nt][2]+bias[nt], v3 = acc[mt][nt][3]+bias[nt];
        if (fast){
          short4 o; o.x=f2bf(v0); o.y=f2bf(v1); o.z=f2bf(v2); o.w=f2bf(v3);
          if (wid == 2) *(short4*)&VhT  [((size_t)b*128 + col)*NH + (m - MM)] = o;
          else          *(short4*)&RESHT[((size_t)b*128 + col)*NH + (m - MM)] = o;
        } else {
          float vv[4] = {v0,v1,v2,v3};
          #pragma unroll
          for (int i=0;i<4;++i){
            int row = rbase + i;
            if (row >= NTOT) continue;
            int bb = row / NSEQ;
            int mm = row - bb*NSEQ;
            if (wid == 2){
              if (mm < MM) VB[((size_t)bb*MM + mm)*128 + col] = f2bf(vv[i]);
              else         VhT[((size_t)bb*128 + col)*NH + (mm - MM)] = f2bf(vv[i]);
            } else {
              if (mm < MM) OUT[((size_t)bb*NSEQ + mm)*128 + col] = vv[i];
              else         RESHT[((size_t)bb*128 + col)*NH + (mm - MM)] = f2bf(vv[i]);
            }
          }
        }
      }
    }
  } else {
    #pragma unroll
    for (int mt=0;mt<2;++mt){
      #pragma unroll
      for (int i=0;i<4;++i){
        int row = m0 + mt*16 + hi*4 + i;
        if (row >= NTOT) continue;
        #pragma unroll
        for (int nt=0;nt<8;++nt){
          float v = acc[mt][nt][i] + bias[nt];
          int col = nt*16 + lo;
          if (wid == 0) QB[(size_t)row*128 + col] = f2bf(v);
          else          KB[(size_t)row*128 + col] = f2bf(v);
        }
      }
    }
  }
}

// ---------------- K1b: V_p^T bf16 (padded) + zero-pad of OP^T tail ----------------
__global__ void k_prep(const short* __restrict__ VB, short* __restrict__ VTb,
                       short* __restrict__ OPTb){
  int b = blockIdx.x, m = blockIdx.y, d = threadIdx.x;  // m<288, d<128
  short vv = (m < MM) ? VB[((size_t)b*MM + m)*128 + d] : (short)0;
  VTb[((size_t)b*128 + d)*MPAD + m] = vv;
  if (m >= MM) OPTb[((size_t)b*128 + d)*MPAD + m] = 0;
}

// ======== macros for attn_p / xp (no lambdas -> arrays stay in registers) ========
#define LOADFR_P(dst, kk, TPTR, tb) do{ \
  _Pragma("unroll") \
  for (int t_=0;t_<2;++t_){ \
    size_t krow_ = kbase + (size_t)((kk) + t_*16 + lo)*128 + hi*8; \
    _Pragma("unroll") \
    for (int ks_=0;ks_<4;++ks_) dst[t_*4+ks_] = *(const bf16x8*)(KB + krow_ + ks_*32); \
  } \
  _Pragma("unroll") \
  for (int nt_=0;nt_<8;++nt_) \
    dst[8+nt_] = *(const bf16x8*)(TPTR + tb + (size_t)(nt_*16 + lo)*NH + (kk) + hi*8); \
}while(0)

// ---------------- K2: MFMA flash attn_p partials (split over keys) ----------------
__global__ __launch_bounds__(64) void k_attnp2(const short* __restrict__ QB,
                        const short* __restrict__ KB, const short* __restrict__ VhT,
                        float* __restrict__ PACC, float* __restrict__ PMX,
                        float* __restrict__ PSM){
  __shared__ short P_lds[16][40];
  int lane = threadIdx.x;
  int lo = lane & 15, hi = lane >> 4;
  int mt = blockIdx.x;   // 0..17
  int s  = blockIdx.y;   // 0..NSP-1
  int b  = blockIdx.z;

  bf16x8 aq[4];
  int qrow = mt*16 + lo;
  if (qrow < MM){
    size_t qb = ((size_t)b*NSEQ + qrow)*128;
    #pragma unroll
    for (int ks=0;ks<4;++ks) aq[ks] = *(const bf16x8*)(QB + qb + ks*32 + hi*8);
  } else {
    #pragma unroll
    for (int ks=0;ks<4;++ks) aq[ks] = bf16x8{0,0,0,0,0,0,0,0};
  }

  float rmax[4], rsum[4];
  #pragma unroll
  for (int i=0;i<4;++i){ rmax[i] = -1e30f; rsum[i] = 0.f; }
  f32x4 acc[8];
  #pragma unroll
  for (int nt=0;nt<8;++nt) acc[nt] = f32x4{0.f,0.f,0.f,0.f};

  const int key0 = s*(NH/NSP);            // 1024 keys per split
  const size_t kbase = ((size_t)b*NSEQ + MM)*128;
  const size_t vbase = (size_t)b*128*NH;

  bf16x8 frA[16], frB[16];

#define BODY_P(cur) do{ \
    f32x4 s0 = {0.f,0.f,0.f,0.f}, s1 = {0.f,0.f,0.f,0.f}; \
    __builtin_amdgcn_s_setprio(1); \
    _Pragma("unroll") \
    for (int ks_=0;ks_<4;++ks_){ \
      s0 = __builtin_amdgcn_mfma_f32_16x16x32_bf16(aq[ks_], cur[ks_],   s0, 0,0,0); \
      s1 = __builtin_amdgcn_mfma_f32_16x16x32_bf16(aq[ks_], cur[4+ks_], s1, 0,0,0); \
    } \
    __builtin_amdgcn_s_setprio(0); \
    _Pragma("unroll") \
    for (int i_=0;i_<4;++i_){ \
      float mc = fmaxf(s0[i_], s1[i_]); \
      _Pragma("unroll") \
      for (int d_=1; d_<16; d_<<=1) mc = fmaxf(mc, __shfl_xor(mc, d_)); \
      float mnew = fmaxf(rmax[i_], mc); \
      float scale = __expf(rmax[i_]-mnew); \
      float p0 = __expf(s0[i_]-mnew), p1 = __expf(s1[i_]-mnew); \
      rsum[i_] = rsum[i_]*scale + p0 + p1; \
      rmax[i_] = mnew; \
      _Pragma("unroll") \
      for (int nt_=0;nt_<8;++nt_) acc[nt_][i_] *= scale; \
      P_lds[hi*4+i_][lo]    = f2bf(p0); \
      P_lds[hi*4+i_][lo+16] = f2bf(p1); \
    } \
    bf16x8 pa = *(const bf16x8*)&P_lds[lo][hi*8]; \
    __builtin_amdgcn_s_setprio(1); \
    _Pragma("unroll") \
    for (int nt_=0;nt_<8;++nt_) \
      acc[nt_] = __builtin_amdgcn_mfma_f32_16x16x32_bf16(pa, cur[8+nt_], acc[nt_], 0,0,0); \
    __builtin_amdgcn_s_setprio(0); \
}while(0)

  LOADFR_P(frA, key0, VhT, vbase);
  #pragma unroll 1
  for (int c = 0; c < 32; c += 2){
    LOADFR_P(frB, key0 + (c+1)*32, VhT, vbase);
    BODY_P(frA);
    if (c+2 < 32) LOADFR_P(frA, key0 + (c+2)*32, VhT, vbase);
    BODY_P(frB);
  }
#undef BODY_P

  #pragma unroll
  for (int i=0;i<4;++i){
    #pragma unroll
    for (int d=1; d<16; d<<=1) rsum[i] += __shfl_xor(rsum[i], d);
  }
  size_t pb = ((size_t)(b*NSP + s)*MPAD + mt*16);
  #pragma unroll
  for (int nt=0;nt<8;++nt)
    #pragma unroll
    for (int i=0;i<4;++i)
      PACC[(pb + hi*4 + i)*128 + nt*16 + lo] = acc[nt][i];
  if (lo == 0){
    #pragma unroll
    for (int i=0;i<4;++i){
      PMX[pb + hi*4 + i] = rmax[i];
      PSM[pb + hi*4 + i] = rsum[i];
    }
  }
}

// ---------------- K3: combine attn_p splits -> OP^T bf16 + final stats ----------------
__global__ void k_pcombine(const float* __restrict__ PACC, const float* __restrict__ PMX,
                           const float* __restrict__ PSM,
                           float* __restrict__ PM, float* __restrict__ PS,
                           short* __restrict__ OPTb){
  int b = blockIdx.x, m = blockIdx.y;   // m < 281
  int d = threadIdx.x;                  // 0..127
  float M = -1e30f;
  #pragma unroll
  for (int s=0;s<NSP;++s) M = fmaxf(M, PMX[((size_t)b*NSP+s)*MPAD+m]);
  float sum = 0.f, a = 0.f;
  #pragma unroll
  for (int s=0;s<NSP;++s){
    size_t pb = ((size_t)b*NSP+s)*MPAD+m;
    float e = __expf(PMX[pb]-M);
    sum += PSM[pb]*e;
    a   += PACC[pb*128+d]*e;
  }
  OPTb[((size_t)b*128+d)*MPAD+m] = f2bf(a/sum);
  if (d==0){ PM[(size_t)b*MPAD+m]=M; PS[(size_t)b*MPAD+m]=sum; }
}

// ---------------- K4: attn_h, register-resident pipeline (macro-unrolled) ----------
__global__ __launch_bounds__(256,3) void k_attnh5(const short* __restrict__ QB,
                        const short* __restrict__ KB,
                        const short* __restrict__ VTb,
                        const short* __restrict__ OPTb,
                        const short* __restrict__ RESHT,
                        short* __restrict__ OHT, float* __restrict__ OUT){
  __shared__ short P_lds[4][16][296];
  int tid = threadIdx.x;
  int wid = tid >> 6, lane = tid & 63;
  int lo = lane & 15, hi = lane >> 4;
  int b = blockIdx.x;
  int q0 = blockIdx.y*64 + wid*16;   // q row within h-block [0,NH)

  bf16x8 aq[4];
  size_t qrow = ((size_t)b*NSEQ + MM + q0 + lo)*128;
  #pragma unroll
  for (int ks=0;ks<4;++ks) aq[ks] = *(const bf16x8*)(QB + qrow + ks*32 + hi*8);

  // residual h-rows (bf16, transposed): issue early, consume in epilogue
  short4 rsh[8];
  #pragma unroll
  for (int nt=0;nt<8;++nt)
    rsh[nt] = *(const short4*)&RESHT[((size_t)b*128 + nt*16 + lo)*NH + q0 + hi*4];

  // ---- S = Q @ Kp^T : 9 chunks of 2 n-tiles, register double buffer ----
  f32x4 s[18];
  #pragma unroll
  for (int nt=0;nt<18;++nt) s[nt] = f32x4{0.f,0.f,0.f,0.f};
  bf16x8 bkA[8], bkB[8];

#define LOADK(dst, c_) do{ \
  _Pragma("unroll") \
  for (int t_=0;t_<2;++t_){ \
    size_t krow_ = ((size_t)b*NSEQ + ((c_)*2+t_)*16 + lo)*128 + hi*8; \
    _Pragma("unroll") \
    for (int ks_=0;ks_<4;++ks_) dst[t_*4+ks_] = *(const bf16x8*)(KB + krow_ + ks_*32); \
  } }while(0)

#define QKCHUNK(cur, c_) do{ \
  __builtin_amdgcn_s_setprio(1); \
  _Pragma("unroll") \
  for (int ks_=0;ks_<4;++ks_){ \
    s[2*(c_)]   = __builtin_amdgcn_mfma_f32_16x16x32_bf16(aq[ks_], cur[ks_],   s[2*(c_)],   0,0,0); \
    s[2*(c_)+1] = __builtin_amdgcn_mfma_f32_16x16x32_bf16(aq[ks_], cur[4+ks_], s[2*(c_)+1], 0,0,0); \
  } \
  __builtin_amdgcn_s_setprio(0); \
}while(0)

  LOADK(bkA, 0);
  LOADK(bkB, 1);
  #pragma unroll
  for (int c=0;c<9;++c){
    if ((c&1)==0){ QKCHUNK(bkA, c); if (c+2<9) LOADK(bkA, c+2); }
    else         { QKCHUNK(bkB, c); if (c+2<9) LOADK(bkB, c+2); }
  }
#undef LOADK
#undef QKCHUNK

  if (lo >= 9){
    s[17][0] = -1e30f; s[17][1] = -1e30f; s[17][2] = -1e30f; s[17][3] = -1e30f;
  }
  // ---- register softmax (unnormalized P; 1/sum deferred) ----
  float rinv4[4];
  #pragma unroll
  for (int i=0;i<4;++i){
    float m = -1e30f;
    #pragma unroll
    for (int nt=0;nt<18;++nt) m = fmaxf(m, s[nt][i]);
    #pragma unroll
    for (int d=1; d<16; d<<=1) m = fmaxf(m, __shfl_xor(m, d));
    float ss = 0.f;
    #pragma unroll
    for (int nt=0;nt<18;++nt){ float w = __expf(s[nt][i]-m); s[nt][i] = w; ss += w; }
    #pragma unroll
    for (int d=1; d<16; d<<=1) ss += __shfl_xor(ss, d);
    rinv4[i] = 1.f/ss;
    int r = hi*4 + i;
    #pragma unroll
    for (int nt=0;nt<18;++nt) P_lds[wid][r][nt*16+lo] = f2bf(s[nt][i]);
  }

  // ---- PV: 2 passes of 4 d-tiles; ks-outer, register double buffer ----
#define LOADV(dst, ks_) do{ \
  _Pragma("unroll") \
  for (int j_=0;j_<4;++j_){ \
    int d_ = (p*4+j_)*16 + lo; \
    dst[j_*2]   = *(const bf16x8*)(VTb  + ((size_t)b*128 + d_)*MPAD + (ks_)*32 + hi*8); \
    dst[j_*2+1] = *(const bf16x8*)(OPTb + ((size_t)b*128 + d_)*MPAD + (ks_)*32 + hi*8); \
  } }while(0)

#define PVCHUNK(cur, ks_) do{ \
  bf16x8 pa_ = *(const bf16x8*)&P_lds[wid][lo][(ks_)*32 + hi*8]; \
  __builtin_amdgcn_s_setprio(1); \
  _Pragma("unroll") \
  for (int j_=0;j_<4;++j_){ \
    aoh[j_] = __builtin_amdgcn_mfma_f32_16x16x32_bf16(pa_, cur[j_*2],   aoh[j_], 0,0,0); \
    axh[j_] = __builtin_amdgcn_mfma_f32_16x16x32_bf16(pa_, cur[j_*2+1], axh[j_], 0,0,0); \
  } \
  __builtin_amdgcn_s_setprio(0); \
}while(0)

  #pragma unroll
  for (int p=0;p<2;++p){
    f32x4 aoh[4], axh[4];
    #pragma unroll
    for (int j=0;j<4;++j){ aoh[j] = f32x4{0.f,0.f,0.f,0.f}; axh[j] = f32x4{0.f,0.f,0.f,0.f}; }
    bf16x8 fvA[8], fvB[8];
    LOADV(fvA, 0);
    LOADV(fvB, 1);
    #pragma unroll
    for (int ks=0;ks<9;++ks){
      if ((ks&1)==0){ PVCHUNK(fvA, ks); if (ks+2<9) LOADV(fvA, ks+2); }
      else          { PVCHUNK(fvB, ks); if (ks+2<9) LOADV(fvB, ks+2); }
    }
    #pragma unroll
    for (int j=0;j<4;++j){
      int nt = p*4 + j;
      int d = nt*16 + lo;
      short4 o;
      o.x = f2bf(aoh[j][0]*rinv4[0]); o.y = f2bf(aoh[j][1]*rinv4[1]);
      o.z = f2bf(aoh[j][2]*rinv4[2]); o.w = f2bf(aoh[j][3]*rinv4[3]);
      *(short4*)&OHT[((size_t)b*128 + d)*NH + q0 + hi*4] = o;
      float r0 = bf2f(rsh[nt].x), r1 = bf2f(rsh[nt].y);
      float r2 = bf2f(rsh[nt].z), r3 = bf2f(rsh[nt].w);
      size_t ob = ((size_t)b*NSEQ + MM + q0 + hi*4)*128 + d;
      OUT[ob        ] = r0 + axh[j][0]*rinv4[0];
      OUT[ob + 128  ] = r1 + axh[j][1]*rinv4[1];
      OUT[ob + 256  ] = r2 + axh[j][2]*rinv4[2];
      OUT[ob + 384  ] = r3 + axh[j][3]*rinv4[3];
    }
  }
#undef LOADV
#undef PVCHUNK
}

// ---------------- K5: xp partials = attn_p @ out_h via MFMA (recomputed weights) -------
__global__ __launch_bounds__(64) void k_xp2(const short* __restrict__ QB,
                     const short* __restrict__ KB, const short* __restrict__ OHT,
                     const float* __restrict__ PM, const float* __restrict__ PS,
                     float* __restrict__ PACC){
  __shared__ short P_lds[16][40];
  int lane = threadIdx.x;
  int lo = lane & 15, hi = lane >> 4;
  int mt = blockIdx.x;   // 0..17
  int s  = blockIdx.y;   // 0..NSP-1
  int b  = blockIdx.z;

  bf16x8 aq[4];
  int qrow = mt*16 + lo;
  if (qrow < MM){
    size_t qb = ((size_t)b*NSEQ + qrow)*128;
    #pragma unroll
    for (int ks=0;ks<4;++ks) aq[ks] = *(const bf16x8*)(QB + qb + ks*32 + hi*8);
  } else {
    #pragma unroll
    for (int ks=0;ks<4;++ks) aq[ks] = bf16x8{0,0,0,0,0,0,0,0};
  }

  float M[4], rinv[4];
  #pragma unroll
  for (int i=0;i<4;++i){
    int row = mt*16 + hi*4 + i;
    if (row < MM){ M[i] = PM[(size_t)b*MPAD+row]; rinv[i] = 1.f/PS[(size_t)b*MPAD+row]; }
    else { M[i] = 0.f; rinv[i] = 0.f; }
  }

  f32x4 acc[8];
  #pragma unroll
  for (int nt=0;nt<8;++nt) acc[nt] = f32x4{0.f,0.f,0.f,0.f};

  const int key0 = s*(NH/NSP);
  const size_t kbase = ((size_t)b*NSEQ + MM)*128;
  const size_t vbase = (size_t)b*128*NH;   // OHT base

  bf16x8 frA[16], frB[16];

#define BODY_X(cur) do{ \
    f32x4 s0 = {0.f,0.f,0.f,0.f}, s1 = {0.f,0.f,0.f,0.f}; \
    __builtin_amdgcn_s_setprio(1); \
    _Pragma("unroll") \
    for (int ks_=0;ks_<4;++ks_){ \
      s0 = __builtin_amdgcn_mfma_f32_16x16x32_bf16(aq[ks_], cur[ks_],   s0, 0,0,0); \
      s1 = __builtin_amdgcn_mfma_f32_16x16x32_bf16(aq[ks_], cur[4+ks_], s1, 0,0,0); \
    } \
    __builtin_amdgcn_s_setprio(0); \
    _Pragma("unroll") \
    for (int i_=0;i_<4;++i_){ \
      float p0 = __expf(s0[i_]-M[i_]), p1 = __expf(s1[i_]-M[i_]); \
      P_lds[hi*4+i_][lo]    = f2bf(p0); \
      P_lds[hi*4+i_][lo+16] = f2bf(p1); \
    } \
    bf16x8 pa = *(const bf16x8*)&P_lds[lo][hi*8]; \
    __builtin_amdgcn_s_setprio(1); \
    _Pragma("unroll") \
    for (int nt_=0;nt_<8;++nt_) \
      acc[nt_] = __builtin_amdgcn_mfma_f32_16x16x32_bf16(pa, cur[8+nt_], acc[nt_], 0,0,0); \
    __builtin_amdgcn_s_setprio(0); \
}while(0)

  LOADFR_P(frA, key0, OHT, vbase);
  #pragma unroll 1
  for (int c = 0; c < 32; c += 2){
    LOADFR_P(frB, key0 + (c+1)*32, OHT, vbase);
    BODY_X(frA);
    if (c+2 < 32) LOADFR_P(frA, key0 + (c+2)*32, OHT, vbase);
    BODY_X(frB);
  }
#undef BODY_X

  size_t pb = ((size_t)(b*NSP + s)*MPAD + mt*16);
  #pragma unroll
  for (int nt=0;nt<8;++nt)
    #pragma unroll
    for (int i=0;i<4;++i)
      PACC[(pb + hi*4 + i)*128 + nt*16 + lo] = acc[nt][i]*rinv[i];
}

// ---------------- K6: deterministic reduction of xp partials into d_out ----------------
__global__ void k_xpreduce(const float* __restrict__ PACC, float* __restrict__ OUT){
  int b = blockIdx.x, m = blockIdx.y;   // m < 281
  int d = threadIdx.x;
  float a = 0.f;
  #pragma unroll
  for (int s=0;s<NSP;++s) a += PACC[(((size_t)b*NSP+s)*MPAD+m)*128+d];
  OUT[((size_t)b*NSEQ+m)*128+d] += a;
}

extern "C" void kernel_launch(void* const* d_in, const int* in_sizes, int n_in,
                              void* d_out, int out_size, void* d_ws, size_t ws_size,
                              hipStream_t stream){
  const float* x    = (const float*)d_in[0];
  const float* qW   = (const float*)d_in[1];
  const float* qb   = (const float*)d_in[2];
  const float* qA   = (const float*)d_in[3];
  const float* qB   = (const float*)d_in[4];
  const float* kvW  = (const float*)d_in[5];
  const float* kvb  = (const float*)d_in[6];
  const float* kvA  = (const float*)d_in[7];
  const float* kvB  = (const float*)d_in[8];
  const float* resW = (const float*)d_in[9];
  const float* resw = (const float*)d_in[10];
  float* out = (float*)d_out;

  char* base = (char*)d_ws;
  size_t off = 0;
  auto alloc = [&](size_t bytes) -> void* {
    void* p = base + off; off += (bytes + 255) & ~(size_t)255; return p;
  };
  short* WcB   = (short*)alloc(512*256*2);
  float* bc    = (float*)alloc(512*4);
  short* XB    = (short*)alloc((size_t)NTOT*256*2);
  short* QB    = (short*)alloc((size_t)NTOT*128*2);
  short* KB    = (short*)alloc((size_t)NTOT*128*2);
  short* VB    = (short*)alloc((size_t)BB*MM*128*2);
  short* VhT   = (short*)alloc((size_t)BB*128*NH*2);
  short* RESHT = (short*)alloc((size_t)BB*128*NH*2);
  short* VTb   = (short*)alloc((size_t)BB*128*MPAD*2);
  short* OPTb  = (short*)alloc((size_t)BB*128*MPAD*2);
  float* PM    = (float*)alloc((size_t)BB*MPAD*4);
  float* PS    = (float*)alloc((size_t)BB*MPAD*4);
  float* PACC  = (float*)alloc((size_t)BB*NSP*MPAD*128*4);
  float* PMX   = (float*)alloc((size_t)BB*NSP*MPAD*4);
  float* PSM   = (float*)alloc((size_t)BB*NSP*MPAD*4);
  short* OHT   = (short*)alloc((size_t)BB*128*NH*2);
  (void)off; (void)ws_size; (void)in_sizes; (void)n_in; (void)out_size;

  k_weights<<<dim3(512), dim3(256), 0, stream>>>(qW,qb,qA,qB,kvW,kvb,kvA,kvB,resW,resw,WcB,bc);
  k_cvtx<<<dim3((int)(((size_t)NTOT*256/8 + 255)/256)), dim3(256), 0, stream>>>(x, XB);
  k_proj3<<<dim3((NTOT+31)/32), dim3(256), 0, stream>>>(XB, WcB, bc, QB, KB, VB, VhT, RESHT, out);
  k_prep<<<dim3(BB, MPAD), dim3(128), 0, stream>>>(VB, VTb, OPTb);
  k_attnp2<<<dim3(18, NSP, BB), dim3(64), 0, stream>>>(QB, KB, VhT, PACC, PMX, PSM);
  k_pcombine<<<dim3(BB, MM), dim3(128), 0, stream>>>(PACC, PMX, PSM, PM, PS, OPTb);
  k_attnh5<<<dim3(BB, NH/64), dim3(256), 0, stream>>>(QB, KB, VTb, OPTb, RESHT, OHT, out);
  k_xp2<<<dim3(18, NSP, BB), dim3(64), 0, stream>>>(QB, KB, OHT, PM, PS, PACC);
  k_xpreduce<<<dim3(BB, MM), dim3(128), 0, stream>>>(PACC, out);
}

// Round 9
// 724.576 us; speedup vs baseline: 1.0532x; 1.0532x over previous
//
#include <hip/hip_runtime.h>
#include <hip/hip_bf16.h>
#include <cstddef>

#define MM     281
#define NSEQ   33049
#define BB     4
#define NH     32768          // NSEQ - MM
#define NTOT   (BB*NSEQ)      // 132196
#define MPAD   288
#define NSP    32             // key splits for p-attention
#define SCALEQ 0.125f
#define LORAS  2.0f

typedef __attribute__((ext_vector_type(8))) short bf16x8;
typedef __attribute__((ext_vector_type(4))) float f32x4;

static __device__ __forceinline__ short f2bf(float v){
  __hip_bfloat16 h = __float2bfloat16(v);
  return *reinterpret_cast<short*>(&h);
}
static __device__ __forceinline__ float bf2f(short v){
  return __uint_as_float((unsigned)(unsigned short)v << 16);
}

// ---------------- K0: fold LoRA + scales into combined bf16 weight matrix ----------------
__global__ void k_weights(const float* __restrict__ qW, const float* __restrict__ qb,
                          const float* __restrict__ qA, const float* __restrict__ qB,
                          const float* __restrict__ kvW, const float* __restrict__ kvb,
                          const float* __restrict__ kvA, const float* __restrict__ kvB,
                          const float* __restrict__ resW, const float* __restrict__ resw,
                          short* __restrict__ WcB, float* __restrict__ bc){
  int j = blockIdx.x;     // 0..511
  int c = threadIdx.x;    // 0..255
  float w;
  if (j < 128){
    float l = 0.f;
    #pragma unroll
    for (int r = 0; r < 8; ++r) l += qA[j*8+r]*qB[r*256+c];
    w = SCALEQ*(qW[j*256+c] + LORAS*l);
    if (c==0) bc[j] = SCALEQ*qb[j];
  } else if (j < 384){
    int jj = j-128;
    float l = 0.f;
    #pragma unroll
    for (int r = 0; r < 8; ++r) l += kvA[jj*8+r]*kvB[r*256+c];
    w = kvW[jj*256+c] + LORAS*l;
    if (c==0) bc[j] = kvb[jj];
  } else {
    int jj = j-384;
    w = resw[0]*resW[jj*256+c];
    if (c==0) bc[j] = 0.f;
  }
  WcB[j*256+c] = f2bf(w);
}

// ---------------- K0b: X f32 -> bf16 (streaming) ----------------
__global__ __launch_bounds__(256) void k_cvtx(const float* __restrict__ X,
                                              short* __restrict__ XB){
  size_t i = ((size_t)blockIdx.x*256 + threadIdx.x)*8;
  if (i >= (size_t)NTOT*256) return;
  float4 u = *(const float4*)(X+i);
  float4 v = *(const float4*)(X+i+4);
  bf16x8 o = bf16x8{f2bf(u.x),f2bf(u.y),f2bf(u.z),f2bf(u.w),
                    f2bf(v.x),f2bf(v.y),f2bf(v.z),f2bf(v.w)};
  *(bf16x8*)(XB+i) = o;
}

// ---------------- K1: MFMA projection GEMM  Y = xb @ Wc.T + bc ----------------
__global__ __launch_bounds__(256) void k_proj3(const short* __restrict__ XB,
                       const short* __restrict__ WcB, const float* __restrict__ bc,
                       short* __restrict__ QB, short* __restrict__ KB,
                       short* __restrict__ VB, short* __restrict__ VhT,
                       short* __restrict__ RESHT, float* __restrict__ OUT){
  int tid = threadIdx.x;
  int wid = tid >> 6, lane = tid & 63;
  int lo = lane & 15, hi = lane >> 4;
  int m0 = blockIdx.x*32;

  f32x4 acc[2][8];
  #pragma unroll
  for (int mt=0;mt<2;++mt)
    #pragma unroll
    for (int nt=0;nt<8;++nt) acc[mt][nt] = f32x4{0.f,0.f,0.f,0.f};

  int r0 = m0 + lo;      if (r0 >= NTOT) r0 = NTOT-1;
  int r1 = m0 + 16 + lo; if (r1 >= NTOT) r1 = NTOT-1;
  const short* x0p = XB + (size_t)r0*256 + hi*8;
  const short* x1p = XB + (size_t)r1*256 + hi*8;

  #pragma unroll
  for (int ks=0; ks<8; ++ks){
    bf16x8 a0 = *(const bf16x8*)(x0p + ks*32);
    bf16x8 a1 = *(const bf16x8*)(x1p + ks*32);
    bf16x8 bfr[8];
    #pragma unroll
    for (int nt=0;nt<8;++nt){
      int jc = wid*128 + nt*16 + lo;
      bfr[nt] = *(const bf16x8*)(WcB + (size_t)jc*256 + ks*32 + hi*8);
    }
    #pragma unroll
    for (int nt=0;nt<8;++nt){
      acc[0][nt] = __builtin_amdgcn_mfma_f32_16x16x32_bf16(a0, bfr[nt], acc[0][nt], 0,0,0);
      acc[1][nt] = __builtin_amdgcn_mfma_f32_16x16x32_bf16(a1, bfr[nt], acc[1][nt], 0,0,0);
    }
  }

  float bias[8];
  #pragma unroll
  for (int nt=0;nt<8;++nt) bias[nt] = bc[wid*128 + nt*16 + lo];

  if (wid == 2 || wid == 3){
    #pragma unroll
    for (int mt=0;mt<2;++mt){
      int rbase = m0 + mt*16 + hi*4;
      int b = rbase / NSEQ;
      int m = rbase - b*NSEQ;
      bool fast = (rbase + 3 < NTOT) && (m >= MM) && (m + 4 <= NSEQ);
      #pragma unroll
      for (int nt=0;nt<8;++nt){
        int col = nt*16 + lo;
        float v0 = acc[mt][nt][0]+bias[nt], v1 = acc[mt][nt][1]+bias[nt];
        float v2 = acc[mt][nt][2]+bias[nt], v3 = acc[mt][nt][3]+bias[nt];
        if (fast){
          short4 o; o.x=f2bf(v0); o.y=f2bf(v1); o.z=f2bf(v2); o.w=f2bf(v3);
          if (wid == 2) *(short4*)&VhT  [((size_t)b*128 + col)*NH + (m - MM)] = o;
          else          *(short4*)&RESHT[((size_t)b*128 + col)*NH + (m - MM)] = o;
        } else {
          float vv[4] = {v0,v1,v2,v3};
          #pragma unroll
          for (int i=0;i<4;++i){
            int row = rbase + i;
            if (row >= NTOT) continue;
            int bb = row / NSEQ;
            int mm = row - bb*NSEQ;
            if (wid == 2){
              if (mm < MM) VB[((size_t)bb*MM + mm)*128 + col] = f2bf(vv[i]);
              else         VhT[((size_t)bb*128 + col)*NH + (mm - MM)] = f2bf(vv[i]);
            } else {
              if (mm < MM) OUT[((size_t)bb*NSEQ + mm)*128 + col] = vv[i];
              else         RESHT[((size_t)bb*128 + col)*NH + (mm - MM)] = f2bf(vv[i]);
            }
          }
        }
      }
    }
  } else {
    #pragma unroll
    for (int mt=0;mt<2;++mt){
      #pragma unroll
      for (int i=0;i<4;++i){
        int row = m0 + mt*16 + hi*4 + i;
        if (row >= NTOT) continue;
        #pragma unroll
        for (int nt=0;nt<8;++nt){
          float v = acc[mt][nt][i] + bias[nt];
          int col = nt*16 + lo;
          if (wid == 0) QB[(size_t)row*128 + col] = f2bf(v);
          else          KB[(size_t)row*128 + col] = f2bf(v);
        }
      }
    }
  }
}

// ---------------- K1b: V_p^T bf16 (padded) + zero-pad of OP^T tail ----------------
__global__ void k_prep(const short* __restrict__ VB, short* __restrict__ VTb,
                       short* __restrict__ OPTb){
  int b = blockIdx.x, m = blockIdx.y, d = threadIdx.x;  // m<288, d<128
  short vv = (m < MM) ? VB[((size_t)b*MM + m)*128 + d] : (short)0;
  VTb[((size_t)b*128 + d)*MPAD + m] = vv;
  if (m >= MM) OPTb[((size_t)b*128 + d)*MPAD + m] = 0;
}

// ======== macros for attn_p / xp (no lambdas -> arrays stay in registers) ========
#define LOADFR_P(dst, kk, TPTR, tb) do{ \
  _Pragma("unroll") \
  for (int t_=0;t_<2;++t_){ \
    size_t krow_ = kbase + (size_t)((kk) + t_*16 + lo)*128 + hi*8; \
    _Pragma("unroll") \
    for (int ks_=0;ks_<4;++ks_) dst[t_*4+ks_] = *(const bf16x8*)(KB + krow_ + ks_*32); \
  } \
  _Pragma("unroll") \
  for (int nt_=0;nt_<8;++nt_) \
    dst[8+nt_] = *(const bf16x8*)(TPTR + tb + (size_t)(nt_*16 + lo)*NH + (kk) + hi*8); \
}while(0)

// ---------------- K2: MFMA flash attn_p partials (split over keys) ----------------
__global__ __launch_bounds__(64) void k_attnp2(const short* __restrict__ QB,
                        const short* __restrict__ KB, const short* __restrict__ VhT,
                        float* __restrict__ PACC, float* __restrict__ PMX,
                        float* __restrict__ PSM){
  __shared__ short P_lds[16][40];
  int lane = threadIdx.x;
  int lo = lane & 15, hi = lane >> 4;
  int mt = blockIdx.x;   // 0..17
  int s  = blockIdx.y;   // 0..NSP-1
  int b  = blockIdx.z;

  bf16x8 aq[4];
  int qrow = mt*16 + lo;
  if (qrow < MM){
    size_t qb = ((size_t)b*NSEQ + qrow)*128;
    #pragma unroll
    for (int ks=0;ks<4;++ks) aq[ks] = *(const bf16x8*)(QB + qb + ks*32 + hi*8);
  } else {
    #pragma unroll
    for (int ks=0;ks<4;++ks) aq[ks] = bf16x8{0,0,0,0,0,0,0,0};
  }

  float rmax[4], rsum[4];
  #pragma unroll
  for (int i=0;i<4;++i){ rmax[i] = -1e30f; rsum[i] = 0.f; }
  f32x4 acc[8];
  #pragma unroll
  for (int nt=0;nt<8;++nt) acc[nt] = f32x4{0.f,0.f,0.f,0.f};

  const int key0 = s*(NH/NSP);            // 1024 keys per split
  const size_t kbase = ((size_t)b*NSEQ + MM)*128;
  const size_t vbase = (size_t)b*128*NH;

  bf16x8 frA[16], frB[16];

#define BODY_P(cur) do{ \
    f32x4 s0 = {0.f,0.f,0.f,0.f}, s1 = {0.f,0.f,0.f,0.f}; \
    __builtin_amdgcn_s_setprio(1); \
    _Pragma("unroll") \
    for (int ks_=0;ks_<4;++ks_){ \
      s0 = __builtin_amdgcn_mfma_f32_16x16x32_bf16(aq[ks_], cur[ks_],   s0, 0,0,0); \
      s1 = __builtin_amdgcn_mfma_f32_16x16x32_bf16(aq[ks_], cur[4+ks_], s1, 0,0,0); \
    } \
    __builtin_amdgcn_s_setprio(0); \
    _Pragma("unroll") \
    for (int i_=0;i_<4;++i_){ \
      float mc = fmaxf(s0[i_], s1[i_]); \
      _Pragma("unroll") \
      for (int d_=1; d_<16; d_<<=1) mc = fmaxf(mc, __shfl_xor(mc, d_)); \
      float mnew = fmaxf(rmax[i_], mc); \
      float scale = __expf(rmax[i_]-mnew); \
      float p0 = __expf(s0[i_]-mnew), p1 = __expf(s1[i_]-mnew); \
      rsum[i_] = rsum[i_]*scale + p0 + p1; \
      rmax[i_] = mnew; \
      _Pragma("unroll") \
      for (int nt_=0;nt_<8;++nt_) acc[nt_][i_] *= scale; \
      P_lds[hi*4+i_][lo]    = f2bf(p0); \
      P_lds[hi*4+i_][lo+16] = f2bf(p1); \
    } \
    bf16x8 pa = *(const bf16x8*)&P_lds[lo][hi*8]; \
    __builtin_amdgcn_s_setprio(1); \
    _Pragma("unroll") \
    for (int nt_=0;nt_<8;++nt_) \
      acc[nt_] = __builtin_amdgcn_mfma_f32_16x16x32_bf16(pa, cur[8+nt_], acc[nt_], 0,0,0); \
    __builtin_amdgcn_s_setprio(0); \
}while(0)

  LOADFR_P(frA, key0, VhT, vbase);
  #pragma unroll 1
  for (int c = 0; c < 32; c += 2){
    LOADFR_P(frB, key0 + (c+1)*32, VhT, vbase);
    BODY_P(frA);
    if (c+2 < 32) LOADFR_P(frA, key0 + (c+2)*32, VhT, vbase);
    BODY_P(frB);
  }
#undef BODY_P

  #pragma unroll
  for (int i=0;i<4;++i){
    #pragma unroll
    for (int d=1; d<16; d<<=1) rsum[i] += __shfl_xor(rsum[i], d);
  }
  size_t pb = ((size_t)(b*NSP + s)*MPAD + mt*16);
  #pragma unroll
  for (int nt=0;nt<8;++nt)
    #pragma unroll
    for (int i=0;i<4;++i)
      PACC[(pb + hi*4 + i)*128 + nt*16 + lo] = acc[nt][i];
  if (lo == 0){
    #pragma unroll
    for (int i=0;i<4;++i){
      PMX[pb + hi*4 + i] = rmax[i];
      PSM[pb + hi*4 + i] = rsum[i];
    }
  }
}

// ---------------- K3: combine attn_p splits -> OP^T bf16 + final stats ----------------
__global__ void k_pcombine(const float* __restrict__ PACC, const float* __restrict__ PMX,
                           const float* __restrict__ PSM,
                           float* __restrict__ PM, float* __restrict__ PS,
                           short* __restrict__ OPTb){
  int b = blockIdx.x, m = blockIdx.y;   // m < 281
  int d = threadIdx.x;                  // 0..127
  float M = -1e30f;
  #pragma unroll
  for (int s=0;s<NSP;++s) M = fmaxf(M, PMX[((size_t)b*NSP+s)*MPAD+m]);
  float sum = 0.f, a = 0.f;
  #pragma unroll
  for (int s=0;s<NSP;++s){
    size_t pb = ((size_t)b*NSP+s)*MPAD+m;
    float e = __expf(PMX[pb]-M);
    sum += PSM[pb]*e;
    a   += PACC[pb*128+d]*e;
  }
  OPTb[((size_t)b*128+d)*MPAD+m] = f2bf(a/sum);
  if (d==0){ PM[(size_t)b*MPAD+m]=M; PS[(size_t)b*MPAD+m]=sum; }
}

// ---------------- K4: attn_h as online-flash (attnp2-style), 9 chunks of 32 keys -------
__global__ __launch_bounds__(256) void k_attnh6(const short* __restrict__ QB,
                        const short* __restrict__ KB,
                        const short* __restrict__ VTb,
                        const short* __restrict__ OPTb,
                        const short* __restrict__ RESHT,
                        short* __restrict__ OHT, float* __restrict__ OUT){
  __shared__ short P_lds[4][16][40];
  int tid = threadIdx.x;
  int wid = tid >> 6, lane = tid & 63;
  int lo = lane & 15, hi = lane >> 4;
  int b = blockIdx.x;
  int q0 = blockIdx.y*64 + wid*16;   // q row within h-block [0,NH)

  bf16x8 aq[4];
  size_t qrow = ((size_t)b*NSEQ + MM + q0 + lo)*128;
  #pragma unroll
  for (int ks=0;ks<4;++ks) aq[ks] = *(const bf16x8*)(QB + qrow + ks*32 + hi*8);

  // residual h-rows (bf16, transposed): issue early, consume in epilogue
  short4 rsh[8];
  #pragma unroll
  for (int nt=0;nt<8;++nt)
    rsh[nt] = *(const short4*)&RESHT[((size_t)b*128 + nt*16 + lo)*NH + q0 + hi*4];

  float rmax[4], rsum[4];
  #pragma unroll
  for (int i=0;i<4;++i){ rmax[i] = -1e30f; rsum[i] = 0.f; }
  f32x4 aoh[8], axh[8];
  #pragma unroll
  for (int nt=0;nt<8;++nt){ aoh[nt] = f32x4{0.f,0.f,0.f,0.f}; axh[nt] = f32x4{0.f,0.f,0.f,0.f}; }

  const size_t kb0 = (size_t)b*NSEQ*128;   // p-keys are rows [0,281) of KB
  const size_t tb0 = (size_t)b*128*MPAD;   // VTb/OPTb [d][key]

  #pragma unroll
  for (int c=0;c<9;++c){
    const int kk = c*32;
    bf16x8 fk[8], fv[8], fo[8];
    #pragma unroll
    for (int t=0;t<2;++t)
      #pragma unroll
      for (int ks=0;ks<4;++ks)
        fk[t*4+ks] = *(const bf16x8*)(KB + kb0 + (size_t)(kk + t*16 + lo)*128 + ks*32 + hi*8);
    #pragma unroll
    for (int nt=0;nt<8;++nt){
      fv[nt] = *(const bf16x8*)(VTb  + tb0 + (size_t)(nt*16 + lo)*MPAD + kk + hi*8);
      fo[nt] = *(const bf16x8*)(OPTb + tb0 + (size_t)(nt*16 + lo)*MPAD + kk + hi*8);
    }
    f32x4 s0 = {0.f,0.f,0.f,0.f}, s1 = {0.f,0.f,0.f,0.f};
    __builtin_amdgcn_s_setprio(1);
    #pragma unroll
    for (int ks=0;ks<4;++ks){
      s0 = __builtin_amdgcn_mfma_f32_16x16x32_bf16(aq[ks], fk[ks],   s0, 0,0,0);
      s1 = __builtin_amdgcn_mfma_f32_16x16x32_bf16(aq[ks], fk[4+ks], s1, 0,0,0);
    }
    __builtin_amdgcn_s_setprio(0);
    if (c == 8 && lo >= 9){  // keys 281..287 invalid
      s1[0] = -1e30f; s1[1] = -1e30f; s1[2] = -1e30f; s1[3] = -1e30f;
    }
    #pragma unroll
    for (int i=0;i<4;++i){
      float mc = fmaxf(s0[i], s1[i]);
      #pragma unroll
      for (int d=1; d<16; d<<=1) mc = fmaxf(mc, __shfl_xor(mc, d));
      float mnew = fmaxf(rmax[i], mc);
      float scale = __expf(rmax[i]-mnew);
      float p0 = __expf(s0[i]-mnew), p1 = __expf(s1[i]-mnew);
      rsum[i] = rsum[i]*scale + p0 + p1;
      rmax[i] = mnew;
      #pragma unroll
      for (int nt=0;nt<8;++nt){ aoh[nt][i] *= scale; axh[nt][i] *= scale; }
      P_lds[wid][hi*4+i][lo]    = f2bf(p0);
      P_lds[wid][hi*4+i][lo+16] = f2bf(p1);
    }
    bf16x8 pa = *(const bf16x8*)&P_lds[wid][lo][hi*8];
    __builtin_amdgcn_s_setprio(1);
    #pragma unroll
    for (int nt=0;nt<8;++nt){
      aoh[nt] = __builtin_amdgcn_mfma_f32_16x16x32_bf16(pa, fv[nt], aoh[nt], 0,0,0);
      axh[nt] = __builtin_amdgcn_mfma_f32_16x16x32_bf16(pa, fo[nt], axh[nt], 0,0,0);
    }
    __builtin_amdgcn_s_setprio(0);
  }

  // epilogue: reduce lane-partial rowsums, deferred normalization, write-only outputs
  #pragma unroll
  for (int i=0;i<4;++i){
    #pragma unroll
    for (int d=1; d<16; d<<=1) rsum[i] += __shfl_xor(rsum[i], d);
  }
  float rinv[4];
  #pragma unroll
  for (int i=0;i<4;++i) rinv[i] = 1.f/rsum[i];
  #pragma unroll
  for (int nt=0;nt<8;++nt){
    int d = nt*16 + lo;
    short4 o;
    o.x = f2bf(aoh[nt][0]*rinv[0]); o.y = f2bf(aoh[nt][1]*rinv[1]);
    o.z = f2bf(aoh[nt][2]*rinv[2]); o.w = f2bf(aoh[nt][3]*rinv[3]);
    *(short4*)&OHT[((size_t)b*128 + d)*NH + q0 + hi*4] = o;
    float r0 = bf2f(rsh[nt].x), r1 = bf2f(rsh[nt].y);
    float r2 = bf2f(rsh[nt].z), r3 = bf2f(rsh[nt].w);
    size_t ob = ((size_t)b*NSEQ + MM + q0 + hi*4)*128 + d;
    OUT[ob      ] = r0 + axh[nt][0]*rinv[0];
    OUT[ob + 128] = r1 + axh[nt][1]*rinv[1];
    OUT[ob + 256] = r2 + axh[nt][2]*rinv[2];
    OUT[ob + 384] = r3 + axh[nt][3]*rinv[3];
  }
}

// ---------------- K5: xp partials = attn_p @ out_h via MFMA (recomputed weights) -------
__global__ __launch_bounds__(64) void k_xp2(const short* __restrict__ QB,
                     const short* __restrict__ KB, const short* __restrict__ OHT,
                     const float* __restrict__ PM, const float* __restrict__ PS,
                     float* __restrict__ PACC){
  __shared__ short P_lds[16][40];
  int lane = threadIdx.x;
  int lo = lane & 15, hi = lane >> 4;
  int mt = blockIdx.x;   // 0..17
  int s  = blockIdx.y;   // 0..NSP-1
  int b  = blockIdx.z;

  bf16x8 aq[4];
  int qrow = mt*16 + lo;
  if (qrow < MM){
    size_t qb = ((size_t)b*NSEQ + qrow)*128;
    #pragma unroll
    for (int ks=0;ks<4;++ks) aq[ks] = *(const bf16x8*)(QB + qb + ks*32 + hi*8);
  } else {
    #pragma unroll
    for (int ks=0;ks<4;++ks) aq[ks] = bf16x8{0,0,0,0,0,0,0,0};
  }

  float M[4], rinv[4];
  #pragma unroll
  for (int i=0;i<4;++i){
    int row = mt*16 + hi*4 + i;
    if (row < MM){ M[i] = PM[(size_t)b*MPAD+row]; rinv[i] = 1.f/PS[(size_t)b*MPAD+row]; }
    else { M[i] = 0.f; rinv[i] = 0.f; }
  }

  f32x4 acc[8];
  #pragma unroll
  for (int nt=0;nt<8;++nt) acc[nt] = f32x4{0.f,0.f,0.f,0.f};

  const int key0 = s*(NH/NSP);
  const size_t kbase = ((size_t)b*NSEQ + MM)*128;
  const size_t vbase = (size_t)b*128*NH;   // OHT base

  bf16x8 frA[16], frB[16];

#define BODY_X(cur) do{ \
    f32x4 s0 = {0.f,0.f,0.f,0.f}, s1 = {0.f,0.f,0.f,0.f}; \
    __builtin_amdgcn_s_setprio(1); \
    _Pragma("unroll") \
    for (int ks_=0;ks_<4;++ks_){ \
      s0 = __builtin_amdgcn_mfma_f32_16x16x32_bf16(aq[ks_], cur[ks_],   s0, 0,0,0); \
      s1 = __builtin_amdgcn_mfma_f32_16x16x32_bf16(aq[ks_], cur[4+ks_], s1, 0,0,0); \
    } \
    __builtin_amdgcn_s_setprio(0); \
    _Pragma("unroll") \
    for (int i_=0;i_<4;++i_){ \
      float p0 = __expf(s0[i_]-M[i_]), p1 = __expf(s1[i_]-M[i_]); \
      P_lds[hi*4+i_][lo]    = f2bf(p0); \
      P_lds[hi*4+i_][lo+16] = f2bf(p1); \
    } \
    bf16x8 pa = *(const bf16x8*)&P_lds[lo][hi*8]; \
    __builtin_amdgcn_s_setprio(1); \
    _Pragma("unroll") \
    for (int nt_=0;nt_<8;++nt_) \
      acc[nt_] = __builtin_amdgcn_mfma_f32_16x16x32_bf16(pa, cur[8+nt_], acc[nt_], 0,0,0); \
    __builtin_amdgcn_s_setprio(0); \
}while(0)

  LOADFR_P(frA, key0, OHT, vbase);
  #pragma unroll 1
  for (int c = 0; c < 32; c += 2){
    LOADFR_P(frB, key0 + (c+1)*32, OHT, vbase);
    BODY_X(frA);
    if (c+2 < 32) LOADFR_P(frA, key0 + (c+2)*32, OHT, vbase);
    BODY_X(frB);
  }
#undef BODY_X

  size_t pb = ((size_t)(b*NSP + s)*MPAD + mt*16);
  #pragma unroll
  for (int nt=0;nt<8;++nt)
    #pragma unroll
    for (int i=0;i<4;++i)
      PACC[(pb + hi*4 + i)*128 + nt*16 + lo] = acc[nt][i]*rinv[i];
}

// ---------------- K6: deterministic reduction of xp partials into d_out ----------------
__global__ void k_xpreduce(const float* __restrict__ PACC, float* __restrict__ OUT){
  int b = blockIdx.x, m = blockIdx.y;   // m < 281
  int d = threadIdx.x;
  float a = 0.f;
  #pragma unroll
  for (int s=0;s<NSP;++s) a += PACC[(((size_t)b*NSP+s)*MPAD+m)*128+d];
  OUT[((size_t)b*NSEQ+m)*128+d] += a;
}

extern "C" void kernel_launch(void* const* d_in, const int* in_sizes, int n_in,
                              void* d_out, int out_size, void* d_ws, size_t ws_size,
                              hipStream_t stream){
  const float* x    = (const float*)d_in[0];
  const float* qW   = (const float*)d_in[1];
  const float* qb   = (const float*)d_in[2];
  const float* qA   = (const float*)d_in[3];
  const float* qB   = (const float*)d_in[4];
  const float* kvW  = (const float*)d_in[5];
  const float* kvb  = (const float*)d_in[6];
  const float* kvA  = (const float*)d_in[7];
  const float* kvB  = (const float*)d_in[8];
  const float* resW = (const float*)d_in[9];
  const float* resw = (const float*)d_in[10];
  float* out = (float*)d_out;

  char* base = (char*)d_ws;
  size_t off = 0;
  auto alloc = [&](size_t bytes) -> void* {
    void* p = base + off; off += (bytes + 255) & ~(size_t)255; return p;
  };
  short* WcB   = (short*)alloc(512*256*2);
  float* bc    = (float*)alloc(512*4);
  short* XB    = (short*)alloc((size_t)NTOT*256*2);
  short* QB    = (short*)alloc((size_t)NTOT*128*2);
  short* KB    = (short*)alloc((size_t)NTOT*128*2);
  short* VB    = (short*)alloc((size_t)BB*MM*128*2);
  short* VhT   = (short*)alloc((size_t)BB*128*NH*2);
  short* RESHT = (short*)alloc((size_t)BB*128*NH*2);
  short* VTb   = (short*)alloc((size_t)BB*128*MPAD*2);
  short* OPTb  = (short*)alloc((size_t)BB*128*MPAD*2);
  float* PM    = (float*)alloc((size_t)BB*MPAD*4);
  float* PS    = (float*)alloc((size_t)BB*MPAD*4);
  float* PACC  = (float*)alloc((size_t)BB*NSP*MPAD*128*4);
  float* PMX   = (float*)alloc((size_t)BB*NSP*MPAD*4);
  float* PSM   = (float*)alloc((size_t)BB*NSP*MPAD*4);
  short* OHT   = (short*)alloc((size_t)BB*128*NH*2);
  (void)off; (void)ws_size; (void)in_sizes; (void)n_in; (void)out_size;

  k_weights<<<dim3(512), dim3(256), 0, stream>>>(qW,qb,qA,qB,kvW,kvb,kvA,kvB,resW,resw,WcB,bc);
  k_cvtx<<<dim3((int)(((size_t)NTOT*256/8 + 255)/256)), dim3(256), 0, stream>>>(x, XB);
  k_proj3<<<dim3((NTOT+31)/32), dim3(256), 0, stream>>>(XB, WcB, bc, QB, KB, VB, VhT, RESHT, out);
  k_prep<<<dim3(BB, MPAD), dim3(128), 0, stream>>>(VB, VTb, OPTb);
  k_attnp2<<<dim3(18, NSP, BB), dim3(64), 0, stream>>>(QB, KB, VhT, PACC, PMX, PSM);
  k_pcombine<<<dim3(BB, MM), dim3(128), 0, stream>>>(PACC, PMX, PSM, PM, PS, OPTb);
  k_attnh6<<<dim3(BB, NH/64), dim3(256), 0, stream>>>(QB, KB, VTb, OPTb, RESHT, OHT, out);
  k_xp2<<<dim3(18, NSP, BB), dim3(64), 0, stream>>>(QB, KB, OHT, PM, PS, PACC);
  k_xpreduce<<<dim3(BB, MM), dim3(128), 0, stream>>>(PACC, out);
}